// Round 1
// baseline (5686.124 us; speedup 1.0000x reference)
//
#include <hip/hip_runtime.h>
#include <hip/hip_fp16.h>

#define T_LEN 512
#define DDIM 512
#define HDIM 512
#define BATCH 64
#define NWG_DIR 32      // workgroups per direction
#define UNITS_PER_WG 16 // hidden units per wg -> 64 gate rows (interleaved [unit][gate])

typedef _Float16 v8h __attribute__((ext_vector_type(8)));
typedef float v4f __attribute__((ext_vector_type(4)));
typedef unsigned int v4u __attribute__((ext_vector_type(4)));

__device__ __forceinline__ float sigf(float x) { return 1.0f / (1.0f + __expf(-x)); }
__device__ __forceinline__ float tanh_fast(float x) { return 2.0f / (1.0f + __expf(-2.0f * x)) - 1.0f; }

// 16B device-coherent load: sc0 sc1 bypass L1+L2 so cross-XCD agent-scope
// producer stores are visible. Caller must s_waitcnt vmcnt + sched_barrier
// before consuming (rule #18: data-dep alone does not order MFMA past the wait).
__device__ __forceinline__ v4u gload16_coh(const void* p) {
  v4u r;
  asm volatile("global_load_dwordx4 %0, %1, off sc0 sc1"
               : "=v"(r) : "v"(p) : "memory");
  return r;
}

// ws layout:
//   [0 .. 8K)        : flags, u32 at (dir*64+sub)*64 bytes — monotonic step count
//   [16K .. 16K+256K): h double buffers: f16 [dir(2)][phase(2)][BATCH][HDIM]
//   [272K ...)       : bw-direction output buffer (f32) when ws permits
// h storage permutation within owner-WG sub: stored half position
// p = sub*16 + q*4 + j holds true unit sub*16 + j*4 + q  (one 8B store/lane).
#define WS_HB_OFF 16384
#define WS_BWOUT_OFF (WS_HB_OFF + 2 * 2 * BATCH * HDIM * 2)
#define OUT_BYTES ((size_t)T_LEN * BATCH * HDIM * 4)
#define WS_NEED_BASE WS_BWOUT_OFF
#define WS_NEED_SPLIT (WS_BWOUT_OFF + OUT_BYTES)

__global__ void __launch_bounds__(256, 1) bilstm_kernel(
    const float* __restrict__ x,
    const float* __restrict__ Wih_fw, const float* __restrict__ Whh_fw,
    const float* __restrict__ Wih_bw, const float* __restrict__ Whh_bw,
    float* __restrict__ out, float* __restrict__ out_bw,
    unsigned char* __restrict__ ws, int split)
{
  const int wg   = blockIdx.x;
  const int dir  = wg >> 5;       // 0 = fw, 1 = bw
  const int sub  = wg & 31;
  const int tid  = threadIdx.x;
  const int w    = tid >> 6;      // wave -> batch block (16 batches)
  const int lane = tid & 63;
  const int n    = lane & 15;     // MFMA col (batch within block) / A-row
  const int q    = lane >> 4;     // MFMA quad
  const int u0   = sub * UNITS_PER_WG;

  // Weights f16, layout [kc(32)][q(4)][r(64)][8]; r = tile*16 + m, rows
  // interleaved m = ulocal*4 + gate (tile covers units u0+tile*4 .. +3).
  // kc<16: Wih. kc>=16: Whh with columns permuted to stored-h order.
  __shared__ _Float16 Wlds[32 * 4 * 64 * 8];  // 128 KiB

  const float* __restrict__ Wih = dir ? Wih_bw : Wih_fw;
  const float* __restrict__ Whh = dir ? Whh_bw : Whh_fw;

  for (int idx = tid; idx < 65536; idx += 256) {
    const int j    = idx & 7;
    const int r    = (idx >> 3) & 63;
    const int qq   = (idx >> 9) & 3;
    const int kc   = idx >> 11;
    const int tile = r >> 4, m = r & 15;
    const int unit = u0 + tile * 4 + (m >> 2);
    const int gate = m & 3;                      // i,f,g,o
    const int R    = gate * HDIM + unit;
    float wv;
    if (kc < 16) {
      const int k = kc * 32 + qq * 8 + j;
      wv = Wih[(size_t)R * DDIM + k];
    } else {
      const int p = (kc - 16) * 32 + qq * 8 + j;                  // stored pos
      const int U = (p & ~15) | (((p & 3) << 2) | ((p >> 2) & 3)); // true unit
      wv = Whh[(size_t)R * HDIM + U];
    }
    Wlds[idx] = (_Float16)wv;
  }
  __syncthreads();

  _Float16* hb = (_Float16*)(ws + WS_HB_OFF) + (size_t)dir * 2 * (BATCH * HDIM);
  unsigned int* flags = (unsigned int*)ws + (size_t)dir * 64 * 16;  // stride 16 u32 = 64 B
  unsigned int* myflag = flags + (size_t)sub * 16;
  const unsigned int* pollflag = flags + (size_t)(tid & 31) * 16;

  float* myout = dir ? out_bw : out;

  const int b = w * 16 + n;   // batch row this lane owns
  float cA = 0.f, cB = 0.f, cC = 0.f, cD = 0.f;  // units u0+{0,4,8,12}+q

  for (int t = 0; t < T_LEN; ++t) {
    const int tx = dir ? (T_LEN - 1 - t) : t;
    const float*    xrow = x + ((size_t)b * T_LEN + tx) * DDIM;
    const _Float16* hrow = hb + (t & 1) * (BATCH * HDIM) + b * HDIM;

    v4f acc0 = {0.f, 0.f, 0.f, 0.f};  // units u0+q,    gates i,f,g,o
    v4f acc1 = {0.f, 0.f, 0.f, 0.f};  // units u0+4+q
    v4f acc2 = {0.f, 0.f, 0.f, 0.f};  // units u0+8+q
    v4f acc3 = {0.f, 0.f, 0.f, 0.f};  // units u0+12+q

    // ---- x phase: independent of h(t); runs before/while producers finish.
    #pragma unroll
    for (int kc = 0; kc < 16; ++kc) {
      const float4 lo = *(const float4*)(xrow + kc * 32 + q * 8);
      const float4 hi = *(const float4*)(xrow + kc * 32 + q * 8 + 4);
      v8h bf;
      bf[0] = (_Float16)lo.x; bf[1] = (_Float16)lo.y; bf[2] = (_Float16)lo.z; bf[3] = (_Float16)lo.w;
      bf[4] = (_Float16)hi.x; bf[5] = (_Float16)hi.y; bf[6] = (_Float16)hi.z; bf[7] = (_Float16)hi.w;
      const _Float16* wb = &Wlds[(size_t)(kc * 4 + q) * 64 * 8];
      const v8h a0 = *(const v8h*)(wb + (n) * 8);
      const v8h a1 = *(const v8h*)(wb + (16 + n) * 8);
      const v8h a2 = *(const v8h*)(wb + (32 + n) * 8);
      const v8h a3 = *(const v8h*)(wb + (48 + n) * 8);
      acc0 = __builtin_amdgcn_mfma_f32_16x16x32_f16(a0, bf, acc0, 0, 0, 0);
      acc1 = __builtin_amdgcn_mfma_f32_16x16x32_f16(a1, bf, acc1, 0, 0, 0);
      acc2 = __builtin_amdgcn_mfma_f32_16x16x32_f16(a2, bf, acc2, 0, 0, 0);
      acc3 = __builtin_amdgcn_mfma_f32_16x16x32_f16(a3, bf, acc3, 0, 0, 0);
    }

    // ---- wait for all 32 producers of this dir to finish step t-1.
    // Wave 0 lanes 0..31 spin on 32 distinct cachelines (no RMW), throttled.
    if (tid < 32) {
      while (__hip_atomic_load(pollflag, __ATOMIC_RELAXED,
                               __HIP_MEMORY_SCOPE_AGENT) < (unsigned int)t) {
        __builtin_amdgcn_s_sleep(2);
      }
    }
    __syncthreads();

    // ---- h phase: 16 x 16B coherent loads per lane (full h row of batch b).
    v4u hu[16];
    #pragma unroll
    for (int kc = 0; kc < 16; ++kc)
      hu[kc] = gload16_coh(hrow + kc * 32 + q * 8);
    asm volatile("s_waitcnt vmcnt(0)" ::: "memory");
    __builtin_amdgcn_sched_barrier(0);

    #pragma unroll
    for (int kc = 16; kc < 32; ++kc) {
      union { v4u u; v8h h; } cv;
      cv.u = hu[kc - 16];
      const _Float16* wb = &Wlds[(size_t)(kc * 4 + q) * 64 * 8];
      const v8h a0 = *(const v8h*)(wb + (n) * 8);
      const v8h a1 = *(const v8h*)(wb + (16 + n) * 8);
      const v8h a2 = *(const v8h*)(wb + (32 + n) * 8);
      const v8h a3 = *(const v8h*)(wb + (48 + n) * 8);
      acc0 = __builtin_amdgcn_mfma_f32_16x16x32_f16(a0, cv.h, acc0, 0, 0, 0);
      acc1 = __builtin_amdgcn_mfma_f32_16x16x32_f16(a1, cv.h, acc1, 0, 0, 0);
      acc2 = __builtin_amdgcn_mfma_f32_16x16x32_f16(a2, cv.h, acc2, 0, 0, 0);
      acc3 = __builtin_amdgcn_mfma_f32_16x16x32_f16(a3, cv.h, acc3, 0, 0, 0);
    }

    // ---- pointwise LSTM cell: all 4 gates lane-local.
    cA = sigf(acc0[1]) * cA + sigf(acc0[0]) * tanh_fast(acc0[2]);
    const float hA = sigf(acc0[3]) * tanh_fast(cA);
    cB = sigf(acc1[1]) * cB + sigf(acc1[0]) * tanh_fast(acc1[2]);
    const float hB = sigf(acc1[3]) * tanh_fast(cB);
    cC = sigf(acc2[1]) * cC + sigf(acc2[0]) * tanh_fast(acc2[2]);
    const float hC = sigf(acc2[3]) * tanh_fast(cC);
    cD = sigf(acc3[1]) * cD + sigf(acc3[0]) * tanh_fast(acc3[2]);
    const float hD = sigf(acc3[3]) * tanh_fast(cD);

    // ---- output: plain L2 stores (split mode) or device atomics (fallback).
    float* orow = myout + ((size_t)tx * BATCH + b) * HDIM;
    if (split) {
      orow[u0 + q]      = hA;
      orow[u0 + 4 + q]  = hB;
      orow[u0 + 8 + q]  = hC;
      orow[u0 + 12 + q] = hD;
    } else {
      __hip_atomic_fetch_add(orow + u0 + q,      hA, __ATOMIC_RELAXED, __HIP_MEMORY_SCOPE_AGENT);
      __hip_atomic_fetch_add(orow + u0 + 4 + q,  hB, __ATOMIC_RELAXED, __HIP_MEMORY_SCOPE_AGENT);
      __hip_atomic_fetch_add(orow + u0 + 8 + q,  hC, __ATOMIC_RELAXED, __HIP_MEMORY_SCOPE_AGENT);
      __hip_atomic_fetch_add(orow + u0 + 12 + q, hD, __ATOMIC_RELAXED, __HIP_MEMORY_SCOPE_AGENT);
    }

    // ---- h exchange: one packed 8B device-coherent store per lane.
    // stored pos sub*16 + q*4 + j  <->  true unit u0 + j*4 + q
    union { _Float16 h[4]; unsigned long long u; } pk;
    pk.h[0] = (_Float16)hA;
    pk.h[1] = (_Float16)hB;
    pk.h[2] = (_Float16)hC;
    pk.h[3] = (_Float16)hD;
    unsigned long long* hw64 =
        (unsigned long long*)(hb + ((t + 1) & 1) * (BATCH * HDIM));
    __hip_atomic_store(&hw64[b * 128 + sub * 4 + q], pk.u,
                       __ATOMIC_RELAXED, __HIP_MEMORY_SCOPE_AGENT);

    // ---- publish: drain own stores, WG-sync, set own flag.
    asm volatile("s_waitcnt vmcnt(0)" ::: "memory");
    __syncthreads();
    if (tid == 0) {
      __hip_atomic_store(myflag, (unsigned int)(t + 1),
                         __ATOMIC_RELAXED, __HIP_MEMORY_SCOPE_AGENT);
    }
  }
}

__global__ void __launch_bounds__(256) add_kernel(float* __restrict__ out,
                                                  const float* __restrict__ addend) {
  const size_t i = ((size_t)blockIdx.x * 256 + threadIdx.x) * 4;
  float4 a = *(const float4*)(out + i);
  const float4 b = *(const float4*)(addend + i);
  a.x += b.x; a.y += b.y; a.z += b.z; a.w += b.w;
  *(float4*)(out + i) = a;
}

extern "C" void kernel_launch(void* const* d_in, const int* in_sizes, int n_in,
                              void* d_out, int out_size, void* d_ws, size_t ws_size,
                              hipStream_t stream) {
  const float* x      = (const float*)d_in[0];
  const float* Wih_fw = (const float*)d_in[1];
  const float* Whh_fw = (const float*)d_in[2];
  const float* Wih_bw = (const float*)d_in[3];
  const float* Whh_bw = (const float*)d_in[4];
  float* out = (float*)d_out;
  unsigned char* ws = (unsigned char*)d_ws;

  const int split = (ws_size >= (size_t)WS_NEED_SPLIT) ? 1 : 0;
  float* out_bw = split ? (float*)(ws + WS_BWOUT_OFF) : out;

  // flags + h buffers must start at 0 (ws is poisoned 0xAA before each call).
  hipMemsetAsync(d_ws, 0, (size_t)WS_NEED_BASE, stream);
  if (!split) {
    hipMemsetAsync(d_out, 0, (size_t)out_size * sizeof(float), stream);
  }

  void* args[] = {(void*)&x, (void*)&Wih_fw, (void*)&Whh_fw, (void*)&Wih_bw,
                  (void*)&Whh_bw, (void*)&out, (void*)&out_bw, (void*)&ws,
                  (void*)&split};
  hipLaunchCooperativeKernel((const void*)bilstm_kernel, dim3(2 * NWG_DIR),
                             dim3(256), args, 0, stream);

  if (split) {
    const int n4 = (int)(OUT_BYTES / 16);
    add_kernel<<<dim3(n4 / 256), dim3(256), 0, stream>>>(out, out_bw);
  }
}

// Round 3
// 3410.209 us; speedup vs baseline: 1.6674x; 1.6674x over previous
//
#include <hip/hip_runtime.h>
#include <hip/hip_fp16.h>

#define T_LEN 512
#define DDIM 512
#define HDIM 512
#define BATCH 64
#define NWG_DIR 32      // workgroups per direction
#define UNITS_PER_WG 16 // hidden units per wg -> 64 gate rows (interleaved [unit][gate])

typedef _Float16 v8h __attribute__((ext_vector_type(8)));
typedef float v4f __attribute__((ext_vector_type(4)));
typedef unsigned int v4u __attribute__((ext_vector_type(4)));

__device__ __forceinline__ float sigf(float x) { return 1.0f / (1.0f + __expf(-x)); }
__device__ __forceinline__ float tanh_fast(float x) { return 2.0f / (1.0f + __expf(-2.0f * x)) - 1.0f; }

// 16B device-coherent load (sc0 sc1 bypass L1+L2 so cross-XCD agent-scope
// producer stores are visible). NO waitcnt inside — caller stages waits.
__device__ __forceinline__ v4u gload16_coh(const void* p) {
  v4u r;
  asm volatile("global_load_dwordx4 %0, %1, off sc0 sc1"
               : "=v"(r) : "v"(p) : "memory");
  return r;
}

// ws layout:
//   [0 .. 1K)        : flags, u32 at [dir(2)][wave(4)][sub(32)] — per-WAVE step count
//   [16K .. 16K+256K): h double buffers: f16 [dir(2)][phase(2)][BATCH][HDIM]
//   [272K ...)       : bw-direction output buffer (f32) when ws permits
// h storage permutation within owner-WG sub: stored half position
// p = sub*16 + q*4 + j holds true unit sub*16 + j*4 + q  (one 8B store/lane).
#define WS_HB_OFF 16384
#define WS_BWOUT_OFF (WS_HB_OFF + 2 * 2 * BATCH * HDIM * 2)
#define OUT_BYTES ((size_t)T_LEN * BATCH * HDIM * 4)
#define WS_NEED_BASE WS_BWOUT_OFF
#define WS_NEED_SPLIT (WS_BWOUT_OFF + OUT_BYTES)

__global__ void __launch_bounds__(256, 1) bilstm_kernel(
    const float* __restrict__ x,
    const float* __restrict__ Wih_fw, const float* __restrict__ Whh_fw,
    const float* __restrict__ Wih_bw, const float* __restrict__ Whh_bw,
    float* __restrict__ out, float* __restrict__ out_bw,
    unsigned char* __restrict__ ws, int split)
{
  const int wg   = blockIdx.x;
  const int dir  = wg >> 5;       // 0 = fw, 1 = bw
  const int sub  = wg & 31;
  const int tid  = threadIdx.x;
  const int w    = tid >> 6;      // wave -> batch block (16 batches)
  const int lane = tid & 63;
  const int n    = lane & 15;     // MFMA col (batch within block) / A-row
  const int q    = lane >> 4;     // MFMA quad
  const int u0   = sub * UNITS_PER_WG;

  // Weights f16, layout [kc(32)][q(4)][r(64)][8]; r = tile*16 + m, rows
  // interleaved m = ulocal*4 + gate (tile covers units u0+tile*4 .. +3).
  // kc<16: Wih. kc>=16: Whh with columns permuted to stored-h order.
  __shared__ _Float16 Wlds[32 * 4 * 64 * 8];  // 128 KiB

  const float* __restrict__ Wih = dir ? Wih_bw : Wih_fw;
  const float* __restrict__ Whh = dir ? Whh_bw : Whh_fw;

  for (int idx = tid; idx < 65536; idx += 256) {
    const int j    = idx & 7;
    const int r    = (idx >> 3) & 63;
    const int qq   = (idx >> 9) & 3;
    const int kc   = idx >> 11;
    const int tile = r >> 4, m = r & 15;
    const int unit = u0 + tile * 4 + (m >> 2);
    const int gate = m & 3;                      // i,f,g,o
    const int R    = gate * HDIM + unit;
    float wv;
    if (kc < 16) {
      const int k = kc * 32 + qq * 8 + j;
      wv = Wih[(size_t)R * DDIM + k];
    } else {
      const int p = (kc - 16) * 32 + qq * 8 + j;                  // stored pos
      const int U = (p & ~15) | (((p & 3) << 2) | ((p >> 2) & 3)); // true unit
      wv = Whh[(size_t)R * HDIM + U];
    }
    Wlds[idx] = (_Float16)wv;
  }
  __syncthreads();   // one-time: weights ready. NO syncthreads inside the loop.

  _Float16* hb = (_Float16*)(ws + WS_HB_OFF) + (size_t)dir * 2 * (BATCH * HDIM);
  // per-wave flags: u32 [dir][w][sub], packed (4B stride) so 8 lanes cover
  // all 32 producer flags of this (dir, wave) with dwordx4 loads.
  unsigned int* flags  = (unsigned int*)ws;
  unsigned int* myflag = flags + (size_t)dir * 128 + (size_t)w * 32 + sub;
  const unsigned int* pollp =
      flags + (size_t)dir * 128 + (size_t)w * 32 + (size_t)(lane & 7) * 4;

  float* myout = dir ? out_bw : out;

  const int b = w * 16 + n;   // batch row this lane owns
  float cA = 0.f, cB = 0.f, cC = 0.f, cD = 0.f;  // units u0+{0,4,8,12}+q

  for (int t = 0; t < T_LEN; ++t) {
    const int tx = dir ? (T_LEN - 1 - t) : t;
    const float*    xrow = x + ((size_t)b * T_LEN + tx) * DDIM;
    const _Float16* hrow = hb + (t & 1) * (BATCH * HDIM) + b * HDIM;

    v4f acc0 = {0.f, 0.f, 0.f, 0.f};  // units u0+q,    gates i,f,g,o
    v4f acc1 = {0.f, 0.f, 0.f, 0.f};  // units u0+4+q
    v4f acc2 = {0.f, 0.f, 0.f, 0.f};  // units u0+8+q
    v4f acc3 = {0.f, 0.f, 0.f, 0.f};  // units u0+12+q

    // ---- x phase: independent of h(t); overlaps producers finishing t-1.
    #pragma unroll
    for (int kc = 0; kc < 16; ++kc) {
      const float4 lo = *(const float4*)(xrow + kc * 32 + q * 8);
      const float4 hi = *(const float4*)(xrow + kc * 32 + q * 8 + 4);
      v8h bf;
      bf[0] = (_Float16)lo.x; bf[1] = (_Float16)lo.y; bf[2] = (_Float16)lo.z; bf[3] = (_Float16)lo.w;
      bf[4] = (_Float16)hi.x; bf[5] = (_Float16)hi.y; bf[6] = (_Float16)hi.z; bf[7] = (_Float16)hi.w;
      const _Float16* wb = &Wlds[(size_t)(kc * 4 + q) * 64 * 8];
      const v8h a0 = *(const v8h*)(wb + (n) * 8);
      const v8h a1 = *(const v8h*)(wb + (16 + n) * 8);
      const v8h a2 = *(const v8h*)(wb + (32 + n) * 8);
      const v8h a3 = *(const v8h*)(wb + (48 + n) * 8);
      acc0 = __builtin_amdgcn_mfma_f32_16x16x32_f16(a0, bf, acc0, 0, 0, 0);
      acc1 = __builtin_amdgcn_mfma_f32_16x16x32_f16(a1, bf, acc1, 0, 0, 0);
      acc2 = __builtin_amdgcn_mfma_f32_16x16x32_f16(a2, bf, acc2, 0, 0, 0);
      acc3 = __builtin_amdgcn_mfma_f32_16x16x32_f16(a3, bf, acc3, 0, 0, 0);
    }

    // ---- wait for wave w of ALL 32 producer WGs (this dir) to finish t-1.
    // All 64 lanes load (8 distinct 16B chunks, coalesced); tight poll.
    // Bounded: converts any unforeseen stall into wrong-answer, not a hang.
    {
      const unsigned int tt = (unsigned int)t;
      unsigned int guard = 0;
      for (;;) {
        v4u f;
        asm volatile("global_load_dwordx4 %0, %1, off sc0 sc1\n\t"
                     "s_waitcnt vmcnt(0)"
                     : "=v"(f) : "v"(pollp) : "memory");
        const bool ok = (f[0] >= tt) & (f[1] >= tt) & (f[2] >= tt) & (f[3] >= tt);
        if (__all(ok)) break;
        if (++guard > (1u << 20)) break;  // safety valve (~0.5 s) — never hit when correct
      }
    }

    // ---- h phase: issue all 16 coherent 16B loads, then consume in 4
    // groups with staged vmcnt so MFMA overlaps outstanding loads.
    v4u hu[16];
    __builtin_amdgcn_sched_barrier(0);
    #pragma unroll
    for (int kc = 0; kc < 16; ++kc)
      hu[kc] = gload16_coh(hrow + kc * 32 + q * 8);

#define HGROUP(G)                                                        \
    _Pragma("unroll")                                                    \
    for (int kk = 0; kk < 4; ++kk) {                                     \
      const int kc = 16 + (G) * 4 + kk;                                  \
      union { v4u u; v8h h; } cv;                                        \
      cv.u = hu[(G) * 4 + kk];                                           \
      const _Float16* wb = &Wlds[(size_t)(kc * 4 + q) * 64 * 8];         \
      const v8h a0 = *(const v8h*)(wb + (n) * 8);                        \
      const v8h a1 = *(const v8h*)(wb + (16 + n) * 8);                   \
      const v8h a2 = *(const v8h*)(wb + (32 + n) * 8);                   \
      const v8h a3 = *(const v8h*)(wb + (48 + n) * 8);                   \
      acc0 = __builtin_amdgcn_mfma_f32_16x16x32_f16(a0, cv.h, acc0, 0, 0, 0); \
      acc1 = __builtin_amdgcn_mfma_f32_16x16x32_f16(a1, cv.h, acc1, 0, 0, 0); \
      acc2 = __builtin_amdgcn_mfma_f32_16x16x32_f16(a2, cv.h, acc2, 0, 0, 0); \
      acc3 = __builtin_amdgcn_mfma_f32_16x16x32_f16(a3, cv.h, acc3, 0, 0, 0); \
    }

    asm volatile("s_waitcnt vmcnt(12)" ::: "memory");
    __builtin_amdgcn_sched_barrier(0);
    HGROUP(0)
    asm volatile("s_waitcnt vmcnt(8)" ::: "memory");
    __builtin_amdgcn_sched_barrier(0);
    HGROUP(1)
    asm volatile("s_waitcnt vmcnt(4)" ::: "memory");
    __builtin_amdgcn_sched_barrier(0);
    HGROUP(2)
    asm volatile("s_waitcnt vmcnt(0)" ::: "memory");
    __builtin_amdgcn_sched_barrier(0);
    HGROUP(3)
#undef HGROUP

    // ---- pointwise LSTM cell: all 4 gates lane-local.
    cA = sigf(acc0[1]) * cA + sigf(acc0[0]) * tanh_fast(acc0[2]);
    const float hA = sigf(acc0[3]) * tanh_fast(cA);
    cB = sigf(acc1[1]) * cB + sigf(acc1[0]) * tanh_fast(acc1[2]);
    const float hB = sigf(acc1[3]) * tanh_fast(cB);
    cC = sigf(acc2[1]) * cC + sigf(acc2[0]) * tanh_fast(acc2[2]);
    const float hC = sigf(acc2[3]) * tanh_fast(cC);
    cD = sigf(acc3[1]) * cD + sigf(acc3[0]) * tanh_fast(acc3[2]);
    const float hD = sigf(acc3[3]) * tanh_fast(cD);

    // ---- h exchange FIRST: one packed 8B device-coherent store per lane,
    // drain ONLY it, publish this wave's flag. Out-stores come after and
    // drain in the shadow of the next step's x-phase.
    // stored pos sub*16 + q*4 + j  <->  true unit u0 + j*4 + q
    union { _Float16 h[4]; unsigned long long u; } pk;
    pk.h[0] = (_Float16)hA;
    pk.h[1] = (_Float16)hB;
    pk.h[2] = (_Float16)hC;
    pk.h[3] = (_Float16)hD;
    unsigned long long* hw64 =
        (unsigned long long*)(hb + ((t + 1) & 1) * (BATCH * HDIM));
    __hip_atomic_store(&hw64[b * 128 + sub * 4 + q], pk.u,
                       __ATOMIC_RELAXED, __HIP_MEMORY_SCOPE_AGENT);
    asm volatile("s_waitcnt vmcnt(0)" ::: "memory");
    if (lane == 0) {
      __hip_atomic_store(myflag, (unsigned int)(t + 1),
                         __ATOMIC_RELAXED, __HIP_MEMORY_SCOPE_AGENT);
    }

    // ---- output: plain L2 stores (split mode) or device atomics (fallback).
    float* orow = myout + ((size_t)tx * BATCH + b) * HDIM;
    if (split) {
      orow[u0 + q]      = hA;
      orow[u0 + 4 + q]  = hB;
      orow[u0 + 8 + q]  = hC;
      orow[u0 + 12 + q] = hD;
    } else {
      __hip_atomic_fetch_add(orow + u0 + q,      hA, __ATOMIC_RELAXED, __HIP_MEMORY_SCOPE_AGENT);
      __hip_atomic_fetch_add(orow + u0 + 4 + q,  hB, __ATOMIC_RELAXED, __HIP_MEMORY_SCOPE_AGENT);
      __hip_atomic_fetch_add(orow + u0 + 8 + q,  hC, __ATOMIC_RELAXED, __HIP_MEMORY_SCOPE_AGENT);
      __hip_atomic_fetch_add(orow + u0 + 12 + q, hD, __ATOMIC_RELAXED, __HIP_MEMORY_SCOPE_AGENT);
    }
  }
}

__global__ void __launch_bounds__(256) add_kernel(float* __restrict__ out,
                                                  const float* __restrict__ addend) {
  const size_t i = ((size_t)blockIdx.x * 256 + threadIdx.x) * 4;
  float4 a = *(const float4*)(out + i);
  const float4 b = *(const float4*)(addend + i);
  a.x += b.x; a.y += b.y; a.z += b.z; a.w += b.w;
  *(float4*)(out + i) = a;
}

extern "C" void kernel_launch(void* const* d_in, const int* in_sizes, int n_in,
                              void* d_out, int out_size, void* d_ws, size_t ws_size,
                              hipStream_t stream) {
  const float* x      = (const float*)d_in[0];
  const float* Wih_fw = (const float*)d_in[1];
  const float* Whh_fw = (const float*)d_in[2];
  const float* Wih_bw = (const float*)d_in[3];
  const float* Whh_bw = (const float*)d_in[4];
  float* out = (float*)d_out;
  unsigned char* ws = (unsigned char*)d_ws;

  const int split = (ws_size >= (size_t)WS_NEED_SPLIT) ? 1 : 0;
  float* out_bw = split ? (float*)(ws + WS_BWOUT_OFF) : out;

  // flags + h buffers must start at 0 (ws is poisoned 0xAA before each call).
  hipMemsetAsync(d_ws, 0, (size_t)WS_NEED_BASE, stream);
  if (!split) {
    hipMemsetAsync(d_out, 0, (size_t)out_size * sizeof(float), stream);
  }

  void* args[] = {(void*)&x, (void*)&Wih_fw, (void*)&Whh_fw, (void*)&Wih_bw,
                  (void*)&Whh_bw, (void*)&out, (void*)&out_bw, (void*)&ws,
                  (void*)&split};
  hipLaunchCooperativeKernel((const void*)bilstm_kernel, dim3(2 * NWG_DIR),
                             dim3(256), args, 0, stream);

  if (split) {
    const int n4 = (int)(OUT_BYTES / 16);
    add_kernel<<<dim3(n4 / 256), dim3(256), 0, stream>>>(out, out_bw);
  }
}

// Round 10
// 3400.706 us; speedup vs baseline: 1.6720x; 1.0028x over previous
//
// v10: round-3 kernel VERBATIM (last known good, 3410 us) + launcher-side
// cooperative-launch error check with plain-launch fallback (co-residency
// is guaranteed by occupancy: 128KB LDS -> 1 WG/CU, 128 WGs < 256 CUs).
#include <hip/hip_runtime.h>
#include <hip/hip_fp16.h>

#define T_LEN 512
#define DDIM 512
#define HDIM 512
#define BATCH 64
#define NWG_DIR 32      // workgroups per direction
#define UNITS_PER_WG 16 // hidden units per wg -> 64 gate rows (interleaved [unit][gate])

typedef _Float16 v8h __attribute__((ext_vector_type(8)));
typedef float v4f __attribute__((ext_vector_type(4)));
typedef unsigned int v4u __attribute__((ext_vector_type(4)));

__device__ __forceinline__ float sigf(float x) { return 1.0f / (1.0f + __expf(-x)); }
__device__ __forceinline__ float tanh_fast(float x) { return 2.0f / (1.0f + __expf(-2.0f * x)) - 1.0f; }

// 16B device-coherent load (sc0 sc1 bypass non-coherent caches so cross-XCD
// agent-scope producer stores are visible). NO waitcnt inside — caller
// stages waits.
__device__ __forceinline__ v4u gload16_coh(const void* p) {
  v4u r;
  asm volatile("global_load_dwordx4 %0, %1, off sc0 sc1"
               : "=v"(r) : "v"(p) : "memory");
  return r;
}

// ws layout:
//   [0 .. 1K)        : flags, u32 at [dir(2)][wave(4)][sub(32)] — per-WAVE step count
//   [16K .. 16K+256K): h double buffers: f16 [dir(2)][phase(2)][BATCH][HDIM]
//   [272K ...)       : bw-direction output buffer (f32) when ws permits
// h storage permutation within owner-WG sub: stored half position
// p = sub*16 + q*4 + j holds true unit sub*16 + j*4 + q  (one 8B store/lane).
#define WS_HB_OFF 16384
#define WS_BWOUT_OFF (WS_HB_OFF + 2 * 2 * BATCH * HDIM * 2)
#define OUT_BYTES ((size_t)T_LEN * BATCH * HDIM * 4)
#define WS_NEED_BASE WS_BWOUT_OFF
#define WS_NEED_SPLIT (WS_BWOUT_OFF + OUT_BYTES)

__global__ void __launch_bounds__(256, 1) bilstm_kernel(
    const float* __restrict__ x,
    const float* __restrict__ Wih_fw, const float* __restrict__ Whh_fw,
    const float* __restrict__ Wih_bw, const float* __restrict__ Whh_bw,
    float* __restrict__ out, float* __restrict__ out_bw,
    unsigned char* __restrict__ ws, int split)
{
  const int wg   = blockIdx.x;
  const int dir  = wg >> 5;       // 0 = fw, 1 = bw
  const int sub  = wg & 31;
  const int tid  = threadIdx.x;
  const int w    = tid >> 6;      // wave -> batch block (16 batches)
  const int lane = tid & 63;
  const int n    = lane & 15;     // MFMA col (batch within block) / A-row
  const int q    = lane >> 4;     // MFMA quad
  const int u0   = sub * UNITS_PER_WG;

  // Weights f16, layout [kc(32)][q(4)][r(64)][8]; r = tile*16 + m, rows
  // interleaved m = ulocal*4 + gate (tile covers units u0+tile*4 .. +3).
  // kc<16: Wih. kc>=16: Whh with columns permuted to stored-h order.
  __shared__ _Float16 Wlds[32 * 4 * 64 * 8];  // 128 KiB

  const float* __restrict__ Wih = dir ? Wih_bw : Wih_fw;
  const float* __restrict__ Whh = dir ? Whh_bw : Whh_fw;

  for (int idx = tid; idx < 65536; idx += 256) {
    const int j    = idx & 7;
    const int r    = (idx >> 3) & 63;
    const int qq   = (idx >> 9) & 3;
    const int kc   = idx >> 11;
    const int tile = r >> 4, m = r & 15;
    const int unit = u0 + tile * 4 + (m >> 2);
    const int gate = m & 3;                      // i,f,g,o
    const int R    = gate * HDIM + unit;
    float wv;
    if (kc < 16) {
      const int k = kc * 32 + qq * 8 + j;
      wv = Wih[(size_t)R * DDIM + k];
    } else {
      const int p = (kc - 16) * 32 + qq * 8 + j;                  // stored pos
      const int U = (p & ~15) | (((p & 3) << 2) | ((p >> 2) & 3)); // true unit
      wv = Whh[(size_t)R * HDIM + U];
    }
    Wlds[idx] = (_Float16)wv;
  }
  __syncthreads();   // one-time: weights ready. NO syncthreads inside the loop.

  _Float16* hb = (_Float16*)(ws + WS_HB_OFF) + (size_t)dir * 2 * (BATCH * HDIM);
  // per-wave flags: u32 [dir][w][sub], packed (4B stride) so 8 lanes cover
  // all 32 producer flags of this (dir, wave) with dwordx4 loads.
  unsigned int* flags  = (unsigned int*)ws;
  unsigned int* myflag = flags + (size_t)dir * 128 + (size_t)w * 32 + sub;
  const unsigned int* pollp =
      flags + (size_t)dir * 128 + (size_t)w * 32 + (size_t)(lane & 7) * 4;

  float* myout = dir ? out_bw : out;

  const int b = w * 16 + n;   // batch row this lane owns
  float cA = 0.f, cB = 0.f, cC = 0.f, cD = 0.f;  // units u0+{0,4,8,12}+q

  for (int t = 0; t < T_LEN; ++t) {
    const int tx = dir ? (T_LEN - 1 - t) : t;
    const float*    xrow = x + ((size_t)b * T_LEN + tx) * DDIM;
    const _Float16* hrow = hb + (t & 1) * (BATCH * HDIM) + b * HDIM;

    v4f acc0 = {0.f, 0.f, 0.f, 0.f};  // units u0+q,    gates i,f,g,o
    v4f acc1 = {0.f, 0.f, 0.f, 0.f};  // units u0+4+q
    v4f acc2 = {0.f, 0.f, 0.f, 0.f};  // units u0+8+q
    v4f acc3 = {0.f, 0.f, 0.f, 0.f};  // units u0+12+q

    // ---- x phase: independent of h(t); overlaps producers finishing t-1.
    #pragma unroll
    for (int kc = 0; kc < 16; ++kc) {
      const float4 lo = *(const float4*)(xrow + kc * 32 + q * 8);
      const float4 hi = *(const float4*)(xrow + kc * 32 + q * 8 + 4);
      v8h bf;
      bf[0] = (_Float16)lo.x; bf[1] = (_Float16)lo.y; bf[2] = (_Float16)lo.z; bf[3] = (_Float16)lo.w;
      bf[4] = (_Float16)hi.x; bf[5] = (_Float16)hi.y; bf[6] = (_Float16)hi.z; bf[7] = (_Float16)hi.w;
      const _Float16* wb = &Wlds[(size_t)(kc * 4 + q) * 64 * 8];
      const v8h a0 = *(const v8h*)(wb + (n) * 8);
      const v8h a1 = *(const v8h*)(wb + (16 + n) * 8);
      const v8h a2 = *(const v8h*)(wb + (32 + n) * 8);
      const v8h a3 = *(const v8h*)(wb + (48 + n) * 8);
      acc0 = __builtin_amdgcn_mfma_f32_16x16x32_f16(a0, bf, acc0, 0, 0, 0);
      acc1 = __builtin_amdgcn_mfma_f32_16x16x32_f16(a1, bf, acc1, 0, 0, 0);
      acc2 = __builtin_amdgcn_mfma_f32_16x16x32_f16(a2, bf, acc2, 0, 0, 0);
      acc3 = __builtin_amdgcn_mfma_f32_16x16x32_f16(a3, bf, acc3, 0, 0, 0);
    }

    // ---- wait for wave w of ALL 32 producer WGs (this dir) to finish t-1.
    // All 64 lanes load (8 distinct 16B chunks, coalesced); tight poll.
    // Bounded: converts any unforeseen stall into wrong-answer, not a hang.
    {
      const unsigned int tt = (unsigned int)t;
      unsigned int guard = 0;
      for (;;) {
        v4u f;
        asm volatile("global_load_dwordx4 %0, %1, off sc0 sc1\n\t"
                     "s_waitcnt vmcnt(0)"
                     : "=v"(f) : "v"(pollp) : "memory");
        const bool ok = (f[0] >= tt) & (f[1] >= tt) & (f[2] >= tt) & (f[3] >= tt);
        if (__all(ok)) break;
        if (++guard > (1u << 20)) break;  // safety valve (~0.5 s) — never hit when correct
      }
    }

    // ---- h phase: issue all 16 coherent 16B loads, then consume in 4
    // groups with staged vmcnt so MFMA overlaps outstanding loads.
    v4u hu[16];
    __builtin_amdgcn_sched_barrier(0);
    #pragma unroll
    for (int kc = 0; kc < 16; ++kc)
      hu[kc] = gload16_coh(hrow + kc * 32 + q * 8);

#define HGROUP(G)                                                        \
    _Pragma("unroll")                                                    \
    for (int kk = 0; kk < 4; ++kk) {                                     \
      const int kc = 16 + (G) * 4 + kk;                                  \
      union { v4u u; v8h h; } cv;                                        \
      cv.u = hu[(G) * 4 + kk];                                           \
      const _Float16* wb = &Wlds[(size_t)(kc * 4 + q) * 64 * 8];         \
      const v8h a0 = *(const v8h*)(wb + (n) * 8);                        \
      const v8h a1 = *(const v8h*)(wb + (16 + n) * 8);                   \
      const v8h a2 = *(const v8h*)(wb + (32 + n) * 8);                   \
      const v8h a3 = *(const v8h*)(wb + (48 + n) * 8);                   \
      acc0 = __builtin_amdgcn_mfma_f32_16x16x32_f16(a0, cv.h, acc0, 0, 0, 0); \
      acc1 = __builtin_amdgcn_mfma_f32_16x16x32_f16(a1, cv.h, acc1, 0, 0, 0); \
      acc2 = __builtin_amdgcn_mfma_f32_16x16x32_f16(a2, cv.h, acc2, 0, 0, 0); \
      acc3 = __builtin_amdgcn_mfma_f32_16x16x32_f16(a3, cv.h, acc3, 0, 0, 0); \
    }

    asm volatile("s_waitcnt vmcnt(12)" ::: "memory");
    __builtin_amdgcn_sched_barrier(0);
    HGROUP(0)
    asm volatile("s_waitcnt vmcnt(8)" ::: "memory");
    __builtin_amdgcn_sched_barrier(0);
    HGROUP(1)
    asm volatile("s_waitcnt vmcnt(4)" ::: "memory");
    __builtin_amdgcn_sched_barrier(0);
    HGROUP(2)
    asm volatile("s_waitcnt vmcnt(0)" ::: "memory");
    __builtin_amdgcn_sched_barrier(0);
    HGROUP(3)
#undef HGROUP

    // ---- pointwise LSTM cell: all 4 gates lane-local.
    cA = sigf(acc0[1]) * cA + sigf(acc0[0]) * tanh_fast(acc0[2]);
    const float hA = sigf(acc0[3]) * tanh_fast(cA);
    cB = sigf(acc1[1]) * cB + sigf(acc1[0]) * tanh_fast(acc1[2]);
    const float hB = sigf(acc1[3]) * tanh_fast(cB);
    cC = sigf(acc2[1]) * cC + sigf(acc2[0]) * tanh_fast(acc2[2]);
    const float hC = sigf(acc2[3]) * tanh_fast(cC);
    cD = sigf(acc3[1]) * cD + sigf(acc3[0]) * tanh_fast(acc3[2]);
    const float hD = sigf(acc3[3]) * tanh_fast(cD);

    // ---- h exchange FIRST: one packed 8B device-coherent store per lane,
    // drain ONLY it, publish this wave's flag. Out-stores come after and
    // drain in the shadow of the next step's x-phase.
    // stored pos sub*16 + q*4 + j  <->  true unit u0 + j*4 + q
    union { _Float16 h[4]; unsigned long long u; } pk;
    pk.h[0] = (_Float16)hA;
    pk.h[1] = (_Float16)hB;
    pk.h[2] = (_Float16)hC;
    pk.h[3] = (_Float16)hD;
    unsigned long long* hw64 =
        (unsigned long long*)(hb + ((t + 1) & 1) * (BATCH * HDIM));
    __hip_atomic_store(&hw64[b * 128 + sub * 4 + q], pk.u,
                       __ATOMIC_RELAXED, __HIP_MEMORY_SCOPE_AGENT);
    asm volatile("s_waitcnt vmcnt(0)" ::: "memory");
    if (lane == 0) {
      __hip_atomic_store(myflag, (unsigned int)(t + 1),
                         __ATOMIC_RELAXED, __HIP_MEMORY_SCOPE_AGENT);
    }

    // ---- output: plain L2 stores (split mode) or device atomics (fallback).
    float* orow = myout + ((size_t)tx * BATCH + b) * HDIM;
    if (split) {
      orow[u0 + q]      = hA;
      orow[u0 + 4 + q]  = hB;
      orow[u0 + 8 + q]  = hC;
      orow[u0 + 12 + q] = hD;
    } else {
      __hip_atomic_fetch_add(orow + u0 + q,      hA, __ATOMIC_RELAXED, __HIP_MEMORY_SCOPE_AGENT);
      __hip_atomic_fetch_add(orow + u0 + 4 + q,  hB, __ATOMIC_RELAXED, __HIP_MEMORY_SCOPE_AGENT);
      __hip_atomic_fetch_add(orow + u0 + 8 + q,  hC, __ATOMIC_RELAXED, __HIP_MEMORY_SCOPE_AGENT);
      __hip_atomic_fetch_add(orow + u0 + 12 + q, hD, __ATOMIC_RELAXED, __HIP_MEMORY_SCOPE_AGENT);
    }
  }
}

__global__ void __launch_bounds__(256) add_kernel(float* __restrict__ out,
                                                  const float* __restrict__ addend) {
  const size_t i = ((size_t)blockIdx.x * 256 + threadIdx.x) * 4;
  float4 a = *(const float4*)(out + i);
  const float4 b = *(const float4*)(addend + i);
  a.x += b.x; a.y += b.y; a.z += b.z; a.w += b.w;
  *(float4*)(out + i) = a;
}

extern "C" void kernel_launch(void* const* d_in, const int* in_sizes, int n_in,
                              void* d_out, int out_size, void* d_ws, size_t ws_size,
                              hipStream_t stream) {
  const float* x      = (const float*)d_in[0];
  const float* Wih_fw = (const float*)d_in[1];
  const float* Whh_fw = (const float*)d_in[2];
  const float* Wih_bw = (const float*)d_in[3];
  const float* Whh_bw = (const float*)d_in[4];
  float* out = (float*)d_out;
  unsigned char* ws = (unsigned char*)d_ws;

  const int split = (ws_size >= (size_t)WS_NEED_SPLIT) ? 1 : 0;
  float* out_bw = split ? (float*)(ws + WS_BWOUT_OFF) : out;

  // flags + h buffers must start at 0 (ws is poisoned 0xAA before each call).
  hipMemsetAsync(d_ws, 0, (size_t)WS_NEED_BASE, stream);
  if (!split) {
    hipMemsetAsync(d_out, 0, (size_t)out_size * sizeof(float), stream);
  }

  void* args[] = {(void*)&x, (void*)&Wih_fw, (void*)&Whh_fw, (void*)&Wih_bw,
                  (void*)&Whh_bw, (void*)&out, (void*)&out_bw, (void*)&ws,
                  (void*)&split};
  hipError_t err = hipLaunchCooperativeKernel(
      (const void*)bilstm_kernel, dim3(2 * NWG_DIR), dim3(256), args, 0, stream);
  if (err != hipSuccess) {
    // Safety net: co-residency is guaranteed by occupancy (128KB LDS ->
    // 1 WG/CU; 128 WGs < 256 CUs), so a plain launch is equivalent.
    bilstm_kernel<<<dim3(2 * NWG_DIR), dim3(256), 0, stream>>>(
        x, Wih_fw, Whh_fw, Wih_bw, Whh_bw, out, out_bw, ws, split);
  }

  if (split) {
    const int n4 = (int)(OUT_BYTES / 16);
    add_kernel<<<dim3(n4 / 256), dim3(256), 0, stream>>>(out, out_bw);
  }
}